// Round 4
// baseline (109.676 us; speedup 1.0000x reference)
//
#include <hip/hip_runtime.h>
#include <math.h>

#define GAMMA 0.3f   // NUM_BASIS/MAX_RADIUS = 3/10

// ---------------------------------------------------------------------------
// K1: W[z,b,h,i] = sum_j rw2[h, i*32+j] * x[z,b,j]
// grid: 256 blocks = z(4) x bgrp(64), 4 b's per block; 256 threads
// ---------------------------------------------------------------------------
__global__ __launch_bounds__(256) void k1_W(const float* __restrict__ x,
                                            const float* __restrict__ rw2,
                                            float* __restrict__ W) {
    int bid = blockIdx.x;
    int z = bid >> 6, bgrp = bid & 63;
    int b0 = bgrp * 4;
    int t = threadIdx.x;
    __shared__ float xs[4][32];
    if (t < 128) {
        int q = t >> 5, j = t & 31;
        xs[q][j] = x[(z * 256 + b0 + q) * 32 + j];
    }
    __syncthreads();
    for (int e = t; e < 3200; e += 256) {
        int h = e >> 5, i = e & 31;
        const float4* w4 = (const float4*)(rw2 + h * 1024 + i * 32);
        float a0 = 0.f, a1 = 0.f, a2 = 0.f, a3 = 0.f;
        #pragma unroll
        for (int j4 = 0; j4 < 8; ++j4) {
            float4 wv = w4[j4];
            int j = j4 * 4;
            a0 += wv.x * xs[0][j] + wv.y * xs[0][j + 1] + wv.z * xs[0][j + 2] + wv.w * xs[0][j + 3];
            a1 += wv.x * xs[1][j] + wv.y * xs[1][j + 1] + wv.z * xs[1][j + 2] + wv.w * xs[1][j + 3];
            a2 += wv.x * xs[2][j] + wv.y * xs[2][j + 1] + wv.z * xs[2][j + 2] + wv.w * xs[2][j + 3];
            a3 += wv.x * xs[3][j] + wv.y * xs[3][j + 1] + wv.z * xs[3][j + 2] + wv.w * xs[3][j + 3];
        }
        W[((z * 256 + b0 + 0) * 100 + h) * 32 + i] = a0;
        W[((z * 256 + b0 + 1) * 100 + h) * 32 + i] = a1;
        W[((z * 256 + b0 + 2) * 100 + h) * 32 + i] = a2;
        W[((z * 256 + b0 + 3) * 100 + h) * 32 + i] = a3;
    }
}

// ---------------------------------------------------------------------------
// K2 primary: grid 2048 = z(4) x bc(64) x hh(2) x ah(4)
// block: 64 a's, 4 b's, 50 h's.  LDS ~14.4 KB -> 8 blocks/CU.
// thread tile 2a x 4i (8 FMA per ds_b64 + glob_b128).
// part[z][q=bc*2+hh][a][i], 128 chunks (16.8 MB)
// ---------------------------------------------------------------------------
__global__ __launch_bounds__(256) void k2_main50(const float* __restrict__ xyz,
                                                 const float* __restrict__ rw1,
                                                 const float* __restrict__ W,
                                                 float* __restrict__ part) {
    int bid = blockIdx.x;
    int ah = bid & 3;
    int hh = (bid >> 2) & 1;
    int bc = (bid >> 3) & 63;
    int z  = bid >> 9;
    int b0 = bc * 4, h0 = hh * 50, a0 = ah * 64;
    int t = threadIdx.x;
    int i_grp = t & 7;    // 4 i's (float4)
    int a_grp = t >> 3;   // 0..31, 2 a's each

    __shared__ __align__(16) float hid[50][64];
    __shared__ float bas[3][64];
    __shared__ float rw1s[304];
    for (int e = t; e < 300; e += 256) rw1s[e] = rw1[e];

    float acc[2][4];
    #pragma unroll
    for (int u = 0; u < 2; ++u)
        #pragma unroll
        for (int v = 0; v < 4; ++v) acc[u][v] = 0.f;

    for (int bi = 0; bi < 4; ++bi) {
        int b = b0 + bi;
        float bx = xyz[(z * 256 + b) * 3 + 0];
        float by = xyz[(z * 256 + b) * 3 + 1];
        float bz = xyz[(z * 256 + b) * 3 + 2];
        __syncthreads();   // prev-phase readers done (and rw1s ready on iter 0)
        if (t < 192) {
            int k = t >> 6, a = t & 63;
            int ga = (z * 256 + a0 + a) * 3;
            float dx = xyz[ga + 0] - bx;
            float dy = xyz[ga + 1] - by;
            float dz = xyz[ga + 2] - bz;
            float rr = sqrtf(dx * dx + dy * dy + dz * dz + 1e-12f);
            float c = rr - 5.f * (float)k;
            bas[k][a] = __expf(-GAMMA * c * c);
        }
        __syncthreads();
        for (int e = t; e < 3200; e += 256) {
            int hl = e >> 6, a = e & 63;
            int h = h0 + hl;
            float pre = bas[0][a] * rw1s[h] + bas[1][a] * rw1s[100 + h] + bas[2][a] * rw1s[200 + h];
            hid[hl][a] = pre * __builtin_amdgcn_rcpf(1.f + __expf(-pre));   // swish
        }
        __syncthreads();
        const float4* wg = (const float4*)(W + (size_t)(z * 256 + b) * 3200 + h0 * 32);
        #pragma unroll 2
        for (int hl = 0; hl < 50; ++hl) {
            float2 hv = *(const float2*)&hid[hl][a_grp * 2];
            float4 wv = wg[hl * 8 + i_grp];
            acc[0][0] += hv.x * wv.x; acc[0][1] += hv.x * wv.y;
            acc[0][2] += hv.x * wv.z; acc[0][3] += hv.x * wv.w;
            acc[1][0] += hv.y * wv.x; acc[1][1] += hv.y * wv.y;
            acc[1][2] += hv.y * wv.z; acc[1][3] += hv.y * wv.w;
        }
    }

    int q = bc * 2 + hh;          // 0..127
    int a = a0 + a_grp * 2;
    size_t base = ((size_t)((z * 128 + q) * 256) + a) * 32 + i_grp * 4;
    *(float4*)&part[base]      = make_float4(acc[0][0], acc[0][1], acc[0][2], acc[0][3]);
    *(float4*)&part[base + 32] = make_float4(acc[1][0], acc[1][1], acc[1][2], acc[1][3]);
}

// ---------------------------------------------------------------------------
// K2 fallback (round-3 proven): grid 1024, 64 chunks, part 8.4 MB
// ---------------------------------------------------------------------------
__global__ __launch_bounds__(256) void k2_main100(const float* __restrict__ xyz,
                                                  const float* __restrict__ rw1,
                                                  const float* __restrict__ W,
                                                  float* __restrict__ part) {
    int bid = blockIdx.x;
    int z = bid >> 8;
    int r = bid & 255;
    int bc = r >> 2, ah = r & 3;
    int b0 = bc * 4, a0 = ah * 64;
    int t = threadIdx.x;
    int i_grp = t & 7;
    int a_grp = t >> 3;

    __shared__ __align__(16) float hid[100][64];
    __shared__ float bas[3][64];
    __shared__ float rw1s[304];
    for (int e = t; e < 300; e += 256) rw1s[e] = rw1[e];

    float acc[2][4];
    #pragma unroll
    for (int u = 0; u < 2; ++u)
        #pragma unroll
        for (int v = 0; v < 4; ++v) acc[u][v] = 0.f;

    for (int bi = 0; bi < 4; ++bi) {
        int b = b0 + bi;
        float bx = xyz[(z * 256 + b) * 3 + 0];
        float by = xyz[(z * 256 + b) * 3 + 1];
        float bz = xyz[(z * 256 + b) * 3 + 2];
        __syncthreads();
        if (t < 192) {
            int k = t >> 6, a = t & 63;
            int ga = (z * 256 + a0 + a) * 3;
            float dx = xyz[ga + 0] - bx;
            float dy = xyz[ga + 1] - by;
            float dz = xyz[ga + 2] - bz;
            float rr = sqrtf(dx * dx + dy * dy + dz * dz + 1e-12f);
            float c = rr - 5.f * (float)k;
            bas[k][a] = __expf(-GAMMA * c * c);
        }
        __syncthreads();
        for (int e = t; e < 6400; e += 256) {
            int h = e >> 6, a = e & 63;
            float pre = bas[0][a] * rw1s[h] + bas[1][a] * rw1s[100 + h] + bas[2][a] * rw1s[200 + h];
            hid[h][a] = pre * __builtin_amdgcn_rcpf(1.f + __expf(-pre));
        }
        __syncthreads();
        const float4* wg = (const float4*)(W + (size_t)(z * 256 + b) * 3200);
        #pragma unroll 2
        for (int h = 0; h < 100; ++h) {
            float2 hv = *(const float2*)&hid[h][a_grp * 2];
            float4 wv = wg[h * 8 + i_grp];
            acc[0][0] += hv.x * wv.x; acc[0][1] += hv.x * wv.y;
            acc[0][2] += hv.x * wv.z; acc[0][3] += hv.x * wv.w;
            acc[1][0] += hv.y * wv.x; acc[1][1] += hv.y * wv.y;
            acc[1][2] += hv.y * wv.z; acc[1][3] += hv.y * wv.w;
        }
    }

    int a = a0 + a_grp * 2;
    size_t base = ((size_t)((z * 64 + bc) * 256) + a) * 32 + i_grp * 4;
    *(float4*)&part[base]      = make_float4(acc[0][0], acc[0][1], acc[0][2], acc[0][3]);
    *(float4*)&part[base + 32] = make_float4(acc[1][0], acc[1][1], acc[1][2], acc[1][3]);
}

// ---------------------------------------------------------------------------
// K3a: sum over nq chunks, abs+mask+scale, pool 4 a's per block.
// grid: 256 blocks = z(4) x ag(64); 256 threads = a_loc(4) x qg(2) x i(32)
// ---------------------------------------------------------------------------
__global__ __launch_bounds__(256) void k3a_reduce(const float* __restrict__ part,
                                                  const int* __restrict__ mask,
                                                  float* __restrict__ pooled_part,
                                                  int nq) {
    int blk = blockIdx.x;
    int z = blk >> 6, ag = blk & 63;
    int t = threadIdx.x;
    int i = t & 31;
    int qg = (t >> 5) & 1;
    int a_loc = t >> 6;               // 0..3
    int a = ag * 4 + a_loc;
    const float* base = part + ((size_t)z * nq * 256 + (size_t)a) * 32 + i;
    float s = 0.f;
    for (int q = qg; q < nq; q += 2)
        s += base[(size_t)q * 8192];
    __shared__ float buf[4][2][32];
    buf[a_loc][qg][i] = s;
    __syncthreads();
    if (t < 128) {
        int al = t >> 5, ii = t & 31;
        float v = buf[al][0][ii] + buf[al][1][ii];
        float sc = (mask[z * 256 + ag * 4 + al] != 0) ? 0.0625f : 0.f;   // 1/sqrt(256)
        buf[al][0][ii] = fabsf(v) * sc;
    }
    __syncthreads();
    if (t < 32) {
        float v = buf[0][0][t] + buf[1][0][t] + buf[2][0][t] + buf[3][0][t];
        pooled_part[(z * 64 + ag) * 32 + t] = v;
    }
}

// ---------------------------------------------------------------------------
// K3b: pool over ag(64), normalize (ddof=1), fc3+leaky, fc2 -> out[4]
// ---------------------------------------------------------------------------
__global__ __launch_bounds__(128) void k3b_final(const float* __restrict__ pooled_part,
                                                 const float* __restrict__ fc3_w,
                                                 const float* __restrict__ fc3_b,
                                                 const float* __restrict__ fc2_w,
                                                 const float* __restrict__ fc2_b,
                                                 float* __restrict__ out) {
    int t = threadIdx.x;
    int z = t >> 5, i = t & 31;
    float s = 0.f;
    for (int ag = 0; ag < 64; ++ag) s += pooled_part[(z * 64 + ag) * 32 + i];
    float sm = s;
    #pragma unroll
    for (int off = 16; off; off >>= 1) sm += __shfl_xor(sm, off, 32);
    float mean = sm * (1.f / 32.f);
    float d = s - mean;
    float ss = d * d;
    #pragma unroll
    for (int off = 16; off; off >>= 1) ss += __shfl_xor(ss, off, 32);
    float stdv = sqrtf(ss * (1.f / 31.f));   // ddof=1
    float nv = d / (stdv + 1e-6f);
    __shared__ float pn[4][32];
    pn[z][i] = nv;
    __syncthreads();
    float h1 = fc3_b[i];
    #pragma unroll
    for (int j = 0; j < 32; ++j) h1 += pn[z][j] * fc3_w[j * 32 + i];
    h1 = (h1 >= 0.f) ? h1 : 0.01f * h1;
    float y = h1 * fc2_w[i];
    #pragma unroll
    for (int off = 16; off; off >>= 1) y += __shfl_xor(y, off, 32);
    if (i == 0) out[z] = y + fc2_b[0];
}

extern "C" void kernel_launch(void* const* d_in, const int* in_sizes, int n_in,
                              void* d_out, int out_size, void* d_ws, size_t ws_size,
                              hipStream_t stream) {
    const float* x    = (const float*)d_in[0];
    const float* xyz  = (const float*)d_in[1];
    const int*   mask = (const int*)d_in[2];
    const float* rw1  = (const float*)d_in[3];
    const float* rw2  = (const float*)d_in[4];
    const float* fc3w = (const float*)d_in[5];
    const float* fc3b = (const float*)d_in[6];
    const float* fc2w = (const float*)d_in[7];
    const float* fc2b = (const float*)d_in[8];
    float* out = (float*)d_out;

    const size_t W_SZ      = (size_t)4 * 256 * 100 * 32 * 4;   // 13,107,200
    const size_t PART128   = (size_t)4 * 128 * 256 * 32 * 4;   // 16,777,216
    const size_t PART64    = (size_t)4 * 64 * 256 * 32 * 4;    //  8,388,608
    const size_t POOLED_SZ = (size_t)4 * 64 * 32 * 4;          //     32,768

    bool big = ws_size >= W_SZ + PART128 + POOLED_SZ;
    float* W    = (float*)d_ws;
    float* part = (float*)((char*)d_ws + W_SZ);
    int nq = big ? 128 : 64;
    float* pooled_part = (float*)((char*)d_ws + W_SZ + (big ? PART128 : PART64));

    hipLaunchKernelGGL(k1_W, dim3(256), dim3(256), 0, stream, x, rw2, W);
    if (big)
        hipLaunchKernelGGL(k2_main50, dim3(2048), dim3(256), 0, stream, xyz, rw1, W, part);
    else
        hipLaunchKernelGGL(k2_main100, dim3(1024), dim3(256), 0, stream, xyz, rw1, W, part);
    hipLaunchKernelGGL(k3a_reduce, dim3(256), dim3(256), 0, stream, part, mask, pooled_part, nq);
    hipLaunchKernelGGL(k3b_final,  dim3(1),   dim3(128), 0, stream, pooled_part, fc3w, fc3b, fc2w, fc2b, out);
}

// Round 5
// 36.373 us; speedup vs baseline: 3.0153x; 3.0153x over previous
//
#include <hip/hip_runtime.h>
#include <math.h>

#define GAMMA 0.3f      // NUM_BASIS / MAX_RADIUS = 3/10
#define WSTR  1604      // Wlds row stride in bf16 elems (1600 + 4 pad: conflict-free ds_read_b64)

typedef __bf16 bf16x8 __attribute__((ext_vector_type(8)));
typedef __bf16 bf16x4 __attribute__((ext_vector_type(4)));
typedef float  f32x4  __attribute__((ext_vector_type(4)));

// ---------------------------------------------------------------------------
// K2 fused: per block (z, bchunk of 16 b's, achunk of 64 a's):
//   phase B: W[b,h,i] = sum_j x[z,b,j]*rw2[h,i*32+j] via MFMA -> LDS bf16 [i][h*16+b]
//   phase C: out_part[a,i] += sum_{k=(h,b)} swish(bas.rw1)[a,k] * W[k,i] via MFMA
// grid 256 = z(4) x bc(16) x ac(4); 256 threads = 4 waves; ~104 KB dynamic LDS
// MFMA fragment layout (16x16x32 bf16):
//   A: lane l holds A[m=l&15][k=(l>>4)*4+e], elems 4..7 at k+16
//   B: lane l holds B[k=(l>>4)*4+e][n=l&15], elems 4..7 at k+16
//   D: col = l&15, row = (l>>4)*4 + reg      (learn_hip m89-verified)
// ---------------------------------------------------------------------------
__global__ __launch_bounds__(256) void k2_fused(const float* __restrict__ x,
                                                const float* __restrict__ xyz,
                                                const float* __restrict__ rw1,
                                                const float* __restrict__ rw2,
                                                float* __restrict__ part) {
    extern __shared__ char smem[];
    __bf16* Wlds = (__bf16*)smem;                     // [32][WSTR] bf16
    float*  rw1s = (float*)(smem + 32 * WSTR * 2);    // [300] f32

    int bid = blockIdx.x;
    int ac = bid & 3;
    int bc = (bid >> 2) & 15;
    int z  = bid >> 6;
    int t  = threadIdx.x;
    int w  = t >> 6;          // wave 0..3
    int l  = t & 63;
    int l16 = l & 15, lg = l >> 4;

    for (int e = t; e < 300; e += 256) rw1s[e] = rw1[e];

    // ---- phase A: per-lane bas registers: a = l&15 row, b-set = lg*4..+3 ----
    int a_glob = ac * 64 + w * 16 + l16;
    float ax = xyz[(z * 256 + a_glob) * 3 + 0];
    float ay = xyz[(z * 256 + a_glob) * 3 + 1];
    float az = xyz[(z * 256 + a_glob) * 3 + 2];
    float bas[4][3];
    #pragma unroll
    for (int e = 0; e < 4; ++e) {
        int b_glob = bc * 16 + lg * 4 + e;
        float dx = xyz[(z * 256 + b_glob) * 3 + 0] - ax;
        float dy = xyz[(z * 256 + b_glob) * 3 + 1] - ay;
        float dz = xyz[(z * 256 + b_glob) * 3 + 2] - az;
        float r  = sqrtf(dx * dx + dy * dy + dz * dz + 1e-12f);
        float r5 = r - 5.f, r10 = r - 10.f;
        bas[e][0] = __expf(-GAMMA * r * r);
        bas[e][1] = __expf(-GAMMA * r5 * r5);
        bas[e][2] = __expf(-GAMMA * r10 * r10);
    }

    // ---- phase B: W chunk via MFMA (M=16 b, N=3200 hi, K=32 j) ----
    bf16x8 xa;
    {
        int row = z * 256 + bc * 16 + l16;
        float4 v0 = *(const float4*)(x + row * 32 + lg * 4);
        float4 v1 = *(const float4*)(x + row * 32 + lg * 4 + 16);
        xa[0] = (__bf16)v0.x; xa[1] = (__bf16)v0.y; xa[2] = (__bf16)v0.z; xa[3] = (__bf16)v0.w;
        xa[4] = (__bf16)v1.x; xa[5] = (__bf16)v1.y; xa[6] = (__bf16)v1.z; xa[7] = (__bf16)v1.w;
    }
    for (int q = 0; q < 50; ++q) {
        int nt = w * 50 + q;                 // n-tile 0..199
        int h  = nt >> 1;
        int icol = ((nt & 1) << 4) + l16;    // i = 0..31
        const float* rp = rw2 + h * 1024 + icol * 32 + lg * 4;
        float4 r0 = *(const float4*)rp;
        float4 r1 = *(const float4*)(rp + 16);
        bf16x8 rb;
        rb[0] = (__bf16)r0.x; rb[1] = (__bf16)r0.y; rb[2] = (__bf16)r0.z; rb[3] = (__bf16)r0.w;
        rb[4] = (__bf16)r1.x; rb[5] = (__bf16)r1.y; rb[6] = (__bf16)r1.z; rb[7] = (__bf16)r1.w;
        f32x4 d = {0.f, 0.f, 0.f, 0.f};
        d = __builtin_amdgcn_mfma_f32_16x16x32_bf16(xa, rb, d, 0, 0, 0);
        #pragma unroll
        for (int r = 0; r < 4; ++r) {
            int k = h * 16 + lg * 4 + r;     // k = h*16 + b_local
            Wlds[icol * WSTR + k] = (__bf16)d[r];
        }
    }
    __syncthreads();

    // ---- phase C: main K loop (1600 k = 100 h x 16 b), 50 MFMA k-steps ----
    f32x4 acc0 = {0.f, 0.f, 0.f, 0.f};
    f32x4 acc1 = {0.f, 0.f, 0.f, 0.f};
    for (int ks = 0; ks < 50; ++ks) {
        int h0 = 2 * ks, h1 = h0 + 1;
        float u00 = rw1s[h0],       u01 = rw1s[h1];
        float u10 = rw1s[100 + h0], u11 = rw1s[100 + h1];
        float u20 = rw1s[200 + h0], u21 = rw1s[200 + h1];
        bf16x8 af;
        #pragma unroll
        for (int e = 0; e < 4; ++e) {
            float p0 = bas[e][0] * u00 + bas[e][1] * u10 + bas[e][2] * u20;
            float p1 = bas[e][0] * u01 + bas[e][1] * u11 + bas[e][2] * u21;
            float s0 = p0 * __builtin_amdgcn_rcpf(1.f + __expf(-p0));   // swish
            float s1 = p1 * __builtin_amdgcn_rcpf(1.f + __expf(-p1));
            af[e]     = (__bf16)s0;    // k-local = lg*4+e  (h0 half)
            af[e + 4] = (__bf16)s1;    // k-local + 16      (h1 half)
        }
        int kb = ks * 32 + lg * 4;
        const __bf16* w0 = &Wlds[l16 * WSTR + kb];
        const __bf16* w1 = &Wlds[(16 + l16) * WSTR + kb];
        bf16x4 b0l = *(const bf16x4*)w0, b0h = *(const bf16x4*)(w0 + 16);
        bf16x4 b1l = *(const bf16x4*)w1, b1h = *(const bf16x4*)(w1 + 16);
        bf16x8 bf0 = __builtin_shufflevector(b0l, b0h, 0, 1, 2, 3, 4, 5, 6, 7);
        bf16x8 bf1 = __builtin_shufflevector(b1l, b1h, 0, 1, 2, 3, 4, 5, 6, 7);
        acc0 = __builtin_amdgcn_mfma_f32_16x16x32_bf16(af, bf0, acc0, 0, 0, 0);
        acc1 = __builtin_amdgcn_mfma_f32_16x16x32_bf16(af, bf1, acc1, 0, 0, 0);
    }

    // ---- phase D: write partials: part[((z*16+bc)*256 + a)*32 + i] ----
    #pragma unroll
    for (int r = 0; r < 4; ++r) {
        int a = ac * 64 + w * 16 + lg * 4 + r;
        size_t base = ((size_t)(z * 16 + bc) * 256 + a) * 32;
        part[base + l16]      = acc0[r];
        part[base + 16 + l16] = acc1[r];
    }
}

// ---------------------------------------------------------------------------
// K3a: sum over nq=16 chunks, abs+mask+scale, pool 4 a's per block.
// grid: 256 blocks = z(4) x ag(64); 256 threads = a_loc(4) x qg(2) x i(32)
// ---------------------------------------------------------------------------
__global__ __launch_bounds__(256) void k3a_reduce(const float* __restrict__ part,
                                                  const int* __restrict__ mask,
                                                  float* __restrict__ pooled_part,
                                                  int nq) {
    int blk = blockIdx.x;
    int z = blk >> 6, ag = blk & 63;
    int t = threadIdx.x;
    int i = t & 31;
    int qg = (t >> 5) & 1;
    int a_loc = t >> 6;               // 0..3
    int a = ag * 4 + a_loc;
    const float* base = part + ((size_t)z * nq * 256 + (size_t)a) * 32 + i;
    float s = 0.f;
    for (int q = qg; q < nq; q += 2)
        s += base[(size_t)q * 8192];
    __shared__ float buf[4][2][32];
    buf[a_loc][qg][i] = s;
    __syncthreads();
    if (t < 128) {
        int al = t >> 5, ii = t & 31;
        float v = buf[al][0][ii] + buf[al][1][ii];
        float sc = (mask[z * 256 + ag * 4 + al] != 0) ? 0.0625f : 0.f;   // 1/sqrt(256)
        buf[al][0][ii] = fabsf(v) * sc;
    }
    __syncthreads();
    if (t < 32) {
        float v = buf[0][0][t] + buf[1][0][t] + buf[2][0][t] + buf[3][0][t];
        pooled_part[(z * 64 + ag) * 32 + t] = v;
    }
}

// ---------------------------------------------------------------------------
// K3b: pool over ag(64), normalize (ddof=1), fc3+leaky, fc2 -> out[4]
// ---------------------------------------------------------------------------
__global__ __launch_bounds__(128) void k3b_final(const float* __restrict__ pooled_part,
                                                 const float* __restrict__ fc3_w,
                                                 const float* __restrict__ fc3_b,
                                                 const float* __restrict__ fc2_w,
                                                 const float* __restrict__ fc2_b,
                                                 float* __restrict__ out) {
    int t = threadIdx.x;
    int z = t >> 5, i = t & 31;
    float s = 0.f;
    for (int ag = 0; ag < 64; ++ag) s += pooled_part[(z * 64 + ag) * 32 + i];
    float sm = s;
    #pragma unroll
    for (int off = 16; off; off >>= 1) sm += __shfl_xor(sm, off, 32);
    float mean = sm * (1.f / 32.f);
    float d = s - mean;
    float ss = d * d;
    #pragma unroll
    for (int off = 16; off; off >>= 1) ss += __shfl_xor(ss, off, 32);
    float stdv = sqrtf(ss * (1.f / 31.f));   // ddof=1
    float nv = d / (stdv + 1e-6f);
    __shared__ float pn[4][32];
    pn[z][i] = nv;
    __syncthreads();
    float h1 = fc3_b[i];
    #pragma unroll
    for (int j = 0; j < 32; ++j) h1 += pn[z][j] * fc3_w[j * 32 + i];
    h1 = (h1 >= 0.f) ? h1 : 0.01f * h1;
    float y = h1 * fc2_w[i];
    #pragma unroll
    for (int off = 16; off; off >>= 1) y += __shfl_xor(y, off, 32);
    if (i == 0) out[z] = y + fc2_b[0];
}

extern "C" void kernel_launch(void* const* d_in, const int* in_sizes, int n_in,
                              void* d_out, int out_size, void* d_ws, size_t ws_size,
                              hipStream_t stream) {
    const float* x    = (const float*)d_in[0];
    const float* xyz  = (const float*)d_in[1];
    const int*   mask = (const int*)d_in[2];
    const float* rw1  = (const float*)d_in[3];
    const float* rw2  = (const float*)d_in[4];
    const float* fc3w = (const float*)d_in[5];
    const float* fc3b = (const float*)d_in[6];
    const float* fc2w = (const float*)d_in[7];
    const float* fc2b = (const float*)d_in[8];
    float* out = (float*)d_out;

    // part: 4 z * 16 bc * 256 a * 32 i * 4 B = 2,097,152 B
    float* part        = (float*)d_ws;
    float* pooled_part = (float*)((char*)d_ws + 2097152);   // 32 KB

    const int LDS_BYTES = 32 * WSTR * 2 + 304 * 4;   // 102,656 + 1,216 = 103,872

    hipLaunchKernelGGL(k2_fused,   dim3(256), dim3(256), LDS_BYTES, stream, x, xyz, rw1, rw2, part);
    hipLaunchKernelGGL(k3a_reduce, dim3(256), dim3(256), 0, stream, part, mask, pooled_part, 16);
    hipLaunchKernelGGL(k3b_final,  dim3(1),   dim3(128), 0, stream, pooled_part, fc3w, fc3b, fc2w, fc2b, out);
}